// Round 2
// baseline (573.147 us; speedup 1.0000x reference)
//
#include <hip/hip_runtime.h>
#include <stdint.h>

typedef __bf16 bf16x8 __attribute__((ext_vector_type(8)));
typedef float f32x4 __attribute__((ext_vector_type(4)));

#define BB 8
#define SS 2048
#define HH 1024

// ws layout (bytes), peak ~167 MiB.
// Q [0,32M) | K [32M,64M) | Vt [64M,96M) | mask [96M,+16K) | TMP [97M, ...)
// TMP phase A (QKV): Xbf(32M) + Wbf(6M) + V(32M)  -> ends ~167 MiB
// TMP phase B (attn, per 4-batch chunk): scores fp32 (64M) -> ends ~161 MiB
#define OFF_Q      0ll
#define OFF_K      33554432ll
#define OFF_VT     67108864ll
#define OFF_MASK   100663296ll
#define OFF_TMP    101711872ll
#define OFF_XBF    (OFF_TMP)
#define OFF_WBF    (OFF_TMP + 33554432ll)
#define OFF_V      (OFF_TMP + 39845888ll)
#define OFF_SCORES (OFF_TMP)

__device__ __forceinline__ unsigned short f2bf(float f) {
  unsigned int u = __float_as_uint(f);
  u += 0x7FFFu + ((u >> 16) & 1u);   // RTNE
  return (unsigned short)(u >> 16);
}

// Detect how the harness pushed the bool mask (uint8 / int32 / float32) from
// the nonzero-byte pattern, write canonical uint8 0/1. Deterministic.
__global__ void canon_mask(const unsigned char* __restrict__ m,
                           unsigned char* __restrict__ out, int n) {
  __shared__ int cnt[4];
  const int t = threadIdx.x;
  if (t < 4) cnt[t] = 0;
  __syncthreads();
  int loc[4] = {0, 0, 0, 0};
  for (int i = t; i < n; i += 256)      // first n bytes: safe for all layouts
    if (m[i] != 0) loc[i & 3]++;
  for (int r = 0; r < 4; ++r)
    if (loc[r]) atomicAdd(&cnt[r], loc[r]);
  __syncthreads();
  const int c0 = cnt[0], c1 = cnt[1], c2 = cnt[2], c3 = cnt[3];
  if (c0 > 0 && c1 == 0 && c2 == 0 && c3 == 0) {        // int32 0/1
    const int* mi = (const int*)m;
    for (int i = t; i < n; i += 256) out[i] = mi[i] ? 1 : 0;
  } else if (c0 == 0 && (c2 > 0 || c3 > 0)) {           // float32 0.0/1.0
    const float* mf = (const float*)m;
    for (int i = t; i < n; i += 256) out[i] = (mf[i] != 0.0f) ? 1 : 0;
  } else {                                              // uint8 bool
    for (int i = t; i < n; i += 256) out[i] = m[i] ? 1 : 0;
  }
}

__global__ void cvt_f32_bf16(const float* __restrict__ in,
                             unsigned short* __restrict__ out, int n4) {
  int i = blockIdx.x * blockDim.x + threadIdx.x;
  int stride = gridDim.x * blockDim.x;
  for (; i < n4; i += stride) {
    float4 v = ((const float4*)in)[i];
    ushort4 o;
    o.x = f2bf(v.x); o.y = f2bf(v.y); o.z = f2bf(v.z); o.w = f2bf(v.w);
    ((ushort4*)out)[i] = o;
  }
}

// V [S,H] -> Vt [H,S] per batch, 32x32 LDS tiles
__global__ void transpose_v(const unsigned short* __restrict__ V,
                            unsigned short* __restrict__ Vt) {
  __shared__ unsigned short t[32][33];
  int b = blockIdx.z;
  const unsigned short* Vb = V + (size_t)b * SS * HH;
  unsigned short* Vtb = Vt + (size_t)b * SS * HH;
  int x0 = blockIdx.x * 32, y0 = blockIdx.y * 32;
  int tx = threadIdx.x, ty = threadIdx.y;
#pragma unroll
  for (int i = 0; i < 4; ++i)
    t[ty + i * 8][tx] = Vb[(size_t)(y0 + ty + i * 8) * HH + x0 + tx];
  __syncthreads();
#pragma unroll
  for (int i = 0; i < 4; ++i)
    Vtb[(size_t)(x0 + ty + i * 8) * SS + y0 + tx] = t[tx][ty + i * 8];
}

#define BM 128
#define BN 128
#define BK 32

__device__ __forceinline__ void gl_lds16(const void* g, void* l) {
  __builtin_amdgcn_global_load_lds(
      (const __attribute__((address_space(1))) void*)g,
      (__attribute__((address_space(3))) void*)l, 16, 0, 0);
}

// C[m,n] = sum_k A[m,k] * B[n,k]   (both operands K-major, m97 structure)
// mode 0: QKV   -> bf16 C = acc + bias[n]
// mode 1: SCORES-> fp32 C = masked(acc/32)  (causal+pad; masked q-row -> 0)
// mode 2: PV    -> fp32 C = acc
__global__ __launch_bounds__(256) void gemm_bt(
    const unsigned short* __restrict__ Abase, long aStride, int lda,
    const unsigned short* __restrict__ Bbase, long bStride, int ldb,
    char* __restrict__ Cbase, long cStrideBytes, int ldc,
    int K, int mode, const float* __restrict__ bias,
    const unsigned char* __restrict__ mask) {
  const int bz = blockIdx.z;
  const unsigned short* A = Abase + (long)bz * aStride;
  const unsigned short* B = Bbase + (long)bz * bStride;
  char* Cb = Cbase + (long)bz * cStrideBytes;

  __shared__ unsigned short As[BM * BK];
  __shared__ unsigned short Bs[BN * BK];

  const int tid = threadIdx.x;
  const int wave = tid >> 6;
  const int lane = tid & 63;
  const int wr = wave >> 1, wc = wave & 1;
  const int lr = lane >> 4, lc = lane & 15;
  const int bm = blockIdx.x, bn = blockIdx.y;

  f32x4 acc[4][4];
  const f32x4 z4 = {0.f, 0.f, 0.f, 0.f};
#pragma unroll
  for (int i = 0; i < 4; ++i)
#pragma unroll
    for (int j = 0; j < 4; ++j) acc[i][j] = z4;

  // strict-upper causal tiles: skip all compute, epilogue writes constants
  const bool skip = (mode == 1) && (bn * BN > bm * BM + (BM - 1));

  if (!skip) {
    const int r0 = tid >> 2;          // 0..63
    const int c8 = (tid & 3) * 8;     // k-elem offset of this thread's 16B
    const unsigned short* aS0 = A + (long)(bm * BM + r0) * lda + c8;
    const unsigned short* aS1 = A + (long)(bm * BM + r0 + 64) * lda + c8;
    const unsigned short* bS0 = B + (long)(bn * BN + r0) * ldb + c8;
    const unsigned short* bS1 = B + (long)(bn * BN + r0 + 64) * ldb + c8;
    char* asL0 = (char*)As + wave * 1024;          // + lane*16 by HW
    char* asL1 = (char*)As + 4096 + wave * 1024;
    char* bsL0 = (char*)Bs + wave * 1024;
    char* bsL1 = (char*)Bs + 4096 + wave * 1024;

    const int kTiles = K / BK;
    for (int kt = 0; kt < kTiles; ++kt) {
      const int ko = kt * BK;
      __syncthreads();                 // prev iter's LDS reads done
      gl_lds16(aS0 + ko, asL0);
      gl_lds16(aS1 + ko, asL1);
      gl_lds16(bS0 + ko, bsL0);
      gl_lds16(bS1 + ko, bsL1);
      __syncthreads();                 // loads landed (vmcnt drain)
      bf16x8 af[4], bg[4];
#pragma unroll
      for (int i = 0; i < 4; ++i)
        af[i] = *(const bf16x8*)(const void*)&As[(wr * 64 + i * 16 + lc) * BK + lr * 8];
#pragma unroll
      for (int j = 0; j < 4; ++j)
        bg[j] = *(const bf16x8*)(const void*)&Bs[(wc * 64 + j * 16 + lc) * BK + lr * 8];
#pragma unroll
      for (int i = 0; i < 4; ++i)
#pragma unroll
        for (int j = 0; j < 4; ++j)
          acc[i][j] = __builtin_amdgcn_mfma_f32_16x16x32_bf16(af[i], bg[j],
                                                              acc[i][j], 0, 0, 0);
    }
  }

  const int rowT = bm * BM + wr * 64;
  const int colT = bn * BN + wc * 64;

  if (mode == 0) {
    unsigned short* C = (unsigned short*)Cb;
#pragma unroll
    for (int j = 0; j < 4; ++j) {
      const int col = colT + j * 16 + lc;
      const float bv = bias[col];
#pragma unroll
      for (int i = 0; i < 4; ++i)
#pragma unroll
        for (int r = 0; r < 4; ++r) {
          const int row = rowT + i * 16 + lr * 4 + r;
          C[(long)row * ldc + col] = f2bf(acc[i][j][r] + bv);
        }
    }
  } else if (mode == 1) {
    float* C = (float*)Cb;
    const unsigned char* mrow = mask + (long)bz * SS;
#pragma unroll
    for (int i = 0; i < 4; ++i)
#pragma unroll
      for (int r = 0; r < 4; ++r) {
        const int q = rowT + i * 16 + lr * 4 + r;
        const bool qm = mrow[q] != 0;
#pragma unroll
        for (int j = 0; j < 4; ++j) {
          const int k = colT + j * 16 + lc;
          float v;
          if (!qm) v = 0.0f;            // masked q-row: uniform softmax
          else if (k <= q && mrow[k]) v = acc[i][j][r] * 0.03125f;
          else v = -1.0e9f;
          C[(long)q * ldc + k] = v;
        }
      }
  } else {
    float* C = (float*)Cb;
#pragma unroll
    for (int i = 0; i < 4; ++i)
#pragma unroll
      for (int j = 0; j < 4; ++j)
#pragma unroll
        for (int r = 0; r < 4; ++r) {
          const int row = rowT + i * 16 + lr * 4 + r;
          const int col = colT + j * 16 + lc;
          C[(long)row * ldc + col] = acc[i][j][r];
        }
  }
}

// row softmax over 2048 fp32, write bf16 in-place (row stride stays 8192B)
__global__ __launch_bounds__(256) void softmax_rows(char* __restrict__ base) {
  const long row = blockIdx.x;
  const float* in = (const float*)(base + row * (SS * 4));
  unsigned short* out = (unsigned short*)(base + row * (SS * 4));
  const int t = threadIdx.x;
  float4 v0 = ((const float4*)in)[t * 2];
  float4 v1 = ((const float4*)in)[t * 2 + 1];
  float v[8] = {v0.x, v0.y, v0.z, v0.w, v1.x, v1.y, v1.z, v1.w};
  float m = v[0];
#pragma unroll
  for (int k = 1; k < 8; ++k) m = fmaxf(m, v[k]);
  __shared__ float red[8];
#pragma unroll
  for (int off = 32; off > 0; off >>= 1) m = fmaxf(m, __shfl_down(m, off, 64));
  const int wid = t >> 6, lane = t & 63;
  if (lane == 0) red[wid] = m;
  __syncthreads();
  m = fmaxf(fmaxf(red[0], red[1]), fmaxf(red[2], red[3]));
  float e[8]; float s = 0.f;
#pragma unroll
  for (int k = 0; k < 8; ++k) { e[k] = __expf(v[k] - m); s += e[k]; }
#pragma unroll
  for (int off = 32; off > 0; off >>= 1) s += __shfl_down(s, off, 64);
  if (lane == 0) red[4 + wid] = s;
  __syncthreads();
  s = red[4] + red[5] + red[6] + red[7];
  const float inv = 1.0f / s;
  ushort4 o0, o1;
  o0.x = f2bf(e[0] * inv); o0.y = f2bf(e[1] * inv);
  o0.z = f2bf(e[2] * inv); o0.w = f2bf(e[3] * inv);
  o1.x = f2bf(e[4] * inv); o1.y = f2bf(e[5] * inv);
  o1.z = f2bf(e[6] * inv); o1.w = f2bf(e[7] * inv);
  ((ushort4*)out)[t * 2] = o0;
  ((ushort4*)out)[t * 2 + 1] = o1;
}

extern "C" void kernel_launch(void* const* d_in, const int* in_sizes, int n_in,
                              void* d_out, int out_size, void* d_ws, size_t ws_size,
                              hipStream_t stream) {
  (void)in_sizes; (void)n_in; (void)out_size; (void)ws_size;
  const float* x = (const float*)d_in[0];
  const unsigned char* mask_raw = (const unsigned char*)d_in[1];
  const float* Wq = (const float*)d_in[2];
  const float* bq = (const float*)d_in[3];
  const float* Wk = (const float*)d_in[4];
  const float* bk = (const float*)d_in[5];
  const float* Wv = (const float*)d_in[6];
  const float* bv = (const float*)d_in[7];
  char* ws = (char*)d_ws;

  unsigned short* Xbf = (unsigned short*)(ws + OFF_XBF);
  unsigned short* Wbf = (unsigned short*)(ws + OFF_WBF);
  unsigned short* Qb = (unsigned short*)(ws + OFF_Q);
  unsigned short* Kb = (unsigned short*)(ws + OFF_K);
  unsigned short* Vb = (unsigned short*)(ws + OFF_V);
  unsigned short* Vt = (unsigned short*)(ws + OFF_VT);
  unsigned char* mask = (unsigned char*)(ws + OFF_MASK);

  const long MS = (long)BB * SS;  // 16384

  // 0. canonicalize mask (auto-detect uint8 / int32 / float32 push format)
  canon_mask<<<1, 256, 0, stream>>>(mask_raw, mask, (int)(BB * SS));

  // 1. fp32 -> bf16 conversions
  cvt_f32_bf16<<<2048, 256, 0, stream>>>(x, Xbf, (int)(MS * HH / 4));
  cvt_f32_bf16<<<256, 256, 0, stream>>>(Wq, Wbf, HH * HH / 4);
  cvt_f32_bf16<<<256, 256, 0, stream>>>(Wk, Wbf + HH * HH, HH * HH / 4);
  cvt_f32_bf16<<<256, 256, 0, stream>>>(Wv, Wbf + 2 * HH * HH, HH * HH / 4);

  // 2. QKV projections: [16384,1024] @ [1024,1024]^T + b
  dim3 gq(MS / BM, HH / BN, 1);
  gemm_bt<<<gq, 256, 0, stream>>>(Xbf, 0, HH, Wbf, 0, HH,
                                  (char*)Qb, 0, HH, HH, 0, bq, nullptr);
  gemm_bt<<<gq, 256, 0, stream>>>(Xbf, 0, HH, Wbf + HH * HH, 0, HH,
                                  (char*)Kb, 0, HH, HH, 0, bk, nullptr);
  gemm_bt<<<gq, 256, 0, stream>>>(Xbf, 0, HH, Wbf + 2 * HH * HH, 0, HH,
                                  (char*)Vb, 0, HH, HH, 0, bv, nullptr);

  // 3. V -> Vt
  transpose_v<<<dim3(HH / 32, SS / 32, BB), dim3(32, 8), 0, stream>>>(Vb, Vt);

  // 4-6. per 4-batch chunk: scores -> softmax -> PV (scores buffer reused)
  for (int c = 0; c < 2; ++c) {
    const long b0 = (long)c * 4;
    dim3 gs(SS / BM, SS / BN, 4);
    gemm_bt<<<gs, 256, 0, stream>>>(Qb + b0 * SS * HH, (long)SS * HH, HH,
                                    Kb + b0 * SS * HH, (long)SS * HH, HH,
                                    ws + OFF_SCORES, (long)SS * SS * 4, SS,
                                    HH, 1, nullptr, mask + b0 * SS);
    softmax_rows<<<4 * SS, 256, 0, stream>>>(ws + OFF_SCORES);
    dim3 gp(SS / BM, HH / BN, 4);
    gemm_bt<<<gp, 256, 0, stream>>>((const unsigned short*)(ws + OFF_SCORES),
                                    (long)SS * 4096, 4096,
                                    Vt + b0 * SS * HH, (long)SS * HH, SS,
                                    (char*)d_out + b0 * SS * HH * 4,
                                    (long)SS * HH * 4, HH,
                                    SS, 2, nullptr, nullptr);
  }
}

// Round 3
// 427.984 us; speedup vs baseline: 1.3392x; 1.3392x over previous
//
#include <hip/hip_runtime.h>
#include <stdint.h>

typedef __bf16 bf16x8 __attribute__((ext_vector_type(8)));
typedef float f32x4 __attribute__((ext_vector_type(4)));

#define BB 8
#define SS 2048
#define HH 1024

#define TILE_B   65536ll          // one 128x128 fp32 tile (row slot = 512B)
#define NTRI     136              // lower-triangle tiles of a 16x16 grid
#define BATCH_B  (NTRI * TILE_B)  // 8,912,896 B compact scores per batch

// ws layout (bytes). Peak = phase A ~167 MiB (same as round 2, known OK).
// Q [0,32M) | K [32M,64M) | Vt [64M,96M) | mask 16K | meanV 32K | TMP [97M..)
// TMP phase A: Xbf(32M)+Wbf(6M)+V(32M) -> ~167 MiB
// TMP phase B: compact scores 8*8.5M = 68 MiB -> ~165 MiB
#define OFF_Q      0ll
#define OFF_K      33554432ll
#define OFF_VT     67108864ll
#define OFF_MASK   100663296ll
#define OFF_MEANV  100679680ll
#define OFF_TMP    101711872ll
#define OFF_XBF    (OFF_TMP)
#define OFF_WBF    (OFF_TMP + 33554432ll)
#define OFF_V      (OFF_TMP + 39845888ll)
#define OFF_SCORES (OFF_TMP)

__device__ __forceinline__ unsigned short f2bf(float f) {
  unsigned int u = __float_as_uint(f);
  u += 0x7FFFu + ((u >> 16) & 1u);   // RTNE
  return (unsigned short)(u >> 16);
}
__device__ __forceinline__ float bf2f(unsigned short u) {
  return __uint_as_float(((unsigned int)u) << 16);
}

// Detect how the harness pushed the bool mask (uint8 / int32 / float32) from
// the nonzero-byte pattern, write canonical uint8 0/1. Deterministic.
__global__ void canon_mask(const unsigned char* __restrict__ m,
                           unsigned char* __restrict__ out, int n) {
  __shared__ int cnt[4];
  const int t = threadIdx.x;
  if (t < 4) cnt[t] = 0;
  __syncthreads();
  int loc[4] = {0, 0, 0, 0};
  for (int i = t; i < n; i += 256)
    if (m[i] != 0) loc[i & 3]++;
  for (int r = 0; r < 4; ++r)
    if (loc[r]) atomicAdd(&cnt[r], loc[r]);
  __syncthreads();
  const int c0 = cnt[0], c1 = cnt[1], c2 = cnt[2], c3 = cnt[3];
  if (c0 > 0 && c1 == 0 && c2 == 0 && c3 == 0) {        // int32 0/1
    const int* mi = (const int*)m;
    for (int i = t; i < n; i += 256) out[i] = mi[i] ? 1 : 0;
  } else if (c0 == 0 && (c2 > 0 || c3 > 0)) {           // float32 0.0/1.0
    const float* mf = (const float*)m;
    for (int i = t; i < n; i += 256) out[i] = (mf[i] != 0.0f) ? 1 : 0;
  } else {                                              // uint8 bool
    for (int i = t; i < n; i += 256) out[i] = m[i] ? 1 : 0;
  }
}

__global__ void cvt_f32_bf16(const float* __restrict__ in,
                             unsigned short* __restrict__ out, int n4) {
  int i = blockIdx.x * blockDim.x + threadIdx.x;
  int stride = gridDim.x * blockDim.x;
  for (; i < n4; i += stride) {
    float4 v = ((const float4*)in)[i];
    ushort4 o;
    o.x = f2bf(v.x); o.y = f2bf(v.y); o.z = f2bf(v.z); o.w = f2bf(v.w);
    ((ushort4*)out)[i] = o;
  }
}

// V [S,H] -> Vt [H,S] per batch, 32x32 LDS tiles
__global__ void transpose_v(const unsigned short* __restrict__ V,
                            unsigned short* __restrict__ Vt) {
  __shared__ unsigned short t[32][33];
  int b = blockIdx.z;
  const unsigned short* Vb = V + (size_t)b * SS * HH;
  unsigned short* Vtb = Vt + (size_t)b * SS * HH;
  int x0 = blockIdx.x * 32, y0 = blockIdx.y * 32;
  int tx = threadIdx.x, ty = threadIdx.y;
#pragma unroll
  for (int i = 0; i < 4; ++i)
    t[ty + i * 8][tx] = Vb[(size_t)(y0 + ty + i * 8) * HH + x0 + tx];
  __syncthreads();
#pragma unroll
  for (int i = 0; i < 4; ++i)
    Vtb[(size_t)(x0 + ty + i * 8) * SS + y0 + tx] = t[tx][ty + i * 8];
}

// per-batch column sums of V via Vt rows: out[b][h] = sum_s V[b][s][h]
__global__ __launch_bounds__(256) void meanv_sum(
    const unsigned short* __restrict__ Vt, float* __restrict__ out) {
  const int b = blockIdx.y;
  const int wave = threadIdx.x >> 6, lane = threadIdx.x & 63;
  const int h = blockIdx.x * 4 + wave;
  const unsigned short* row = Vt + ((long)b * HH + h) * SS;
  float s = 0.f;
#pragma unroll
  for (int j = 0; j < 4; ++j) {
    const ushort4* p = (const ushort4*)(row + j * 512 + lane * 8);
    ushort4 u0 = p[0], u1 = p[1];
    s += bf2f(u0.x) + bf2f(u0.y) + bf2f(u0.z) + bf2f(u0.w)
       + bf2f(u1.x) + bf2f(u1.y) + bf2f(u1.z) + bf2f(u1.w);
  }
#pragma unroll
  for (int off = 32; off > 0; off >>= 1) s += __shfl_down(s, off, 64);
  if (lane == 0) out[(long)b * HH + h] = s;
}

// overwrite masked query rows with meanV (uniform attention over all keys)
__global__ __launch_bounds__(256) void fixup_masked(
    float* __restrict__ out, const unsigned char* __restrict__ mask,
    const float* __restrict__ sums) {
  const long row = blockIdx.x;
  if (mask[row]) return;
  const long b = row >> 11;
  const int t = threadIdx.x;
  float4 v = ((const float4*)(sums + b * HH))[t];
  v.x *= (1.f / 2048.f); v.y *= (1.f / 2048.f);
  v.z *= (1.f / 2048.f); v.w *= (1.f / 2048.f);
  ((float4*)(out + row * HH))[t] = v;
}

#define BM 128
#define BN 128
#define BK 32

__device__ __forceinline__ void gl_lds16(const void* g, void* l) {
  __builtin_amdgcn_global_load_lds(
      (const __attribute__((address_space(1))) void*)g,
      (__attribute__((address_space(3))) void*)l, 16, 0, 0);
}

// C[m,n] = sum_k A[m,k] * B[n,k]   (K-major operands, m97 structure)
// mode 0: fused QKV. grid (M/128, 8, 3); z picks {W,bias,C}; bf16 C=acc+bias
// mode 1: SCORES. grid (136,1,B); blockIdx.x = triangular tile id;
//         compact fp32 write masked(acc/32) (causal+pad; masked q-row -> 0)
// mode 2: PV. A = compact triangular bf16 attn (row slot 512B);
//         kTiles = (bm+1)*4 (causal limit); fp32 C = acc
__global__ __launch_bounds__(256) void gemm_bt(
    const unsigned short* __restrict__ Abase, long aStride, int lda,
    const unsigned short* __restrict__ Bbase, long bStride, int ldb,
    char* __restrict__ C0, char* __restrict__ C1, char* __restrict__ C2,
    long cStrideBytes, int ldc, int K, int mode,
    const float* __restrict__ bias0, const float* __restrict__ bias1,
    const float* __restrict__ bias2,
    const unsigned char* __restrict__ mask) {
  const int bz = blockIdx.z;
  int bm = blockIdx.x, bn = blockIdx.y;
  int triIdx = 0;
  if (mode == 1) {                       // triangular decode
    const int t = bm;
    bm = (int)((sqrtf(8.0f * (float)t + 1.0f) - 1.0f) * 0.5f);
    while ((bm + 1) * (bm + 2) / 2 <= t) ++bm;
    while (bm * (bm + 1) / 2 > t) --bm;
    bn = t - bm * (bm + 1) / 2;
    triIdx = t;
  }
  const unsigned short* A = Abase + (long)bz * aStride;
  const unsigned short* B = Bbase + (long)bz * bStride;

  __shared__ unsigned short As[BM * BK];
  __shared__ unsigned short Bs[BN * BK];

  const int tid = threadIdx.x;
  const int wave = tid >> 6;
  const int lane = tid & 63;
  const int wr = wave >> 1, wc = wave & 1;
  const int lr = lane >> 4, lc = lane & 15;

  f32x4 acc[4][4];
  const f32x4 z4 = {0.f, 0.f, 0.f, 0.f};
#pragma unroll
  for (int i = 0; i < 4; ++i)
#pragma unroll
    for (int j = 0; j < 4; ++j) acc[i][j] = z4;

  const int r0 = tid >> 2;          // 0..63
  const int c8 = (tid & 3) * 8;     // k-elem offset of this thread's 16B
  char* asL0 = (char*)As + wave * 1024;          // + lane*16 by HW
  char* asL1 = (char*)As + 4096 + wave * 1024;
  char* bsL0 = (char*)Bs + wave * 1024;
  char* bsL1 = (char*)Bs + 4096 + wave * 1024;

  const unsigned short* bS0 = B + (long)(bn * BN + r0) * ldb + c8;
  const unsigned short* bS1 = B + (long)(bn * BN + r0 + 64) * ldb + c8;

  const char *aP0, *aP1;
  if (mode == 2) {   // compact triangular A: tile row slot = 512B, bf16 cols
    const char* Ac = (const char*)A + (long)(bm * (bm + 1) / 2) * TILE_B;
    aP0 = Ac + (long)r0 * 512 + c8 * 2;
    aP1 = Ac + (long)(r0 + 64) * 512 + c8 * 2;
  } else {
    aP0 = (const char*)(A + (long)(bm * BM + r0) * lda + c8);
    aP1 = (const char*)(A + (long)(bm * BM + r0 + 64) * lda + c8);
  }

  const int kTiles = (mode == 2) ? (bm + 1) * (BM / BK) : (K / BK);
  for (int kt = 0; kt < kTiles; ++kt) {
    const int ko = kt * BK;
    long offA;
    if (mode == 2) offA = (long)(ko >> 7) * TILE_B + (long)(ko & 127) * 2;
    else           offA = (long)ko * 2;
    __syncthreads();                 // prev iter's LDS reads done
    gl_lds16(aP0 + offA, asL0);
    gl_lds16(aP1 + offA, asL1);
    gl_lds16((const void*)(bS0 + ko), bsL0);
    gl_lds16((const void*)(bS1 + ko), bsL1);
    __syncthreads();                 // loads landed
    bf16x8 af[4], bg[4];
#pragma unroll
    for (int i = 0; i < 4; ++i)
      af[i] = *(const bf16x8*)(const void*)&As[(wr * 64 + i * 16 + lc) * BK + lr * 8];
#pragma unroll
    for (int j = 0; j < 4; ++j)
      bg[j] = *(const bf16x8*)(const void*)&Bs[(wc * 64 + j * 16 + lc) * BK + lr * 8];
#pragma unroll
    for (int i = 0; i < 4; ++i)
#pragma unroll
      for (int j = 0; j < 4; ++j)
        acc[i][j] = __builtin_amdgcn_mfma_f32_16x16x32_bf16(af[i], bg[j],
                                                            acc[i][j], 0, 0, 0);
  }

  const int rT = wr * 64;   // local row base within the 128-tile
  const int cT = wc * 64;   // local col base

  if (mode == 0) {
    const float* bias = (bz == 0) ? bias0 : (bz == 1) ? bias1 : bias2;
    unsigned short* C = (unsigned short*)((bz == 0) ? C0 : (bz == 1) ? C1 : C2);
#pragma unroll
    for (int j = 0; j < 4; ++j) {
      const int col = bn * BN + cT + j * 16 + lc;
      const float bv = bias[col];
#pragma unroll
      for (int i = 0; i < 4; ++i)
#pragma unroll
        for (int r = 0; r < 4; ++r) {
          const int row = bm * BM + rT + i * 16 + lr * 4 + r;
          C[(long)row * ldc + col] = f2bf(acc[i][j][r] + bv);
        }
    }
  } else if (mode == 1) {
    float* Ct = (float*)(C0 + (long)bz * cStrideBytes + (long)triIdx * TILE_B);
    const unsigned char* mrow = mask + (long)bz * SS;
#pragma unroll
    for (int i = 0; i < 4; ++i)
#pragma unroll
      for (int r = 0; r < 4; ++r) {
        const int ql = rT + i * 16 + lr * 4 + r;
        const int q = bm * BM + ql;
        const bool qm = mrow[q] != 0;
#pragma unroll
        for (int j = 0; j < 4; ++j) {
          const int kl = cT + j * 16 + lc;
          const int k = bn * BN + kl;
          float v;
          if (!qm) v = 0.0f;            // masked q-row: fixup overwrites out
          else if (k <= q && mrow[k]) v = acc[i][j][r] * 0.03125f;
          else v = -1.0e9f;
          Ct[ql * 128 + kl] = v;
        }
      }
  } else {
    float* C = (float*)(C0 + (long)bz * cStrideBytes);
#pragma unroll
    for (int i = 0; i < 4; ++i)
#pragma unroll
      for (int j = 0; j < 4; ++j)
#pragma unroll
        for (int r = 0; r < 4; ++r) {
          const int row = bm * BM + rT + i * 16 + lr * 4 + r;
          const int col = bn * BN + cT + j * 16 + lc;
          C[(long)row * ldc + col] = acc[i][j][r];
        }
  }
}

// softmax over causal prefix of one row; compact tiles; in-place fp32->bf16
// (bf16 goes to first 256B of the row's private 512B slot -> race-free)
__global__ __launch_bounds__(256) void softmax_tri(char* __restrict__ base) {
  const int r = blockIdx.x;           // row within batch
  const int bz = blockIdx.y;          // batch
  const int bm = r >> 7;
  const int w = (bm + 1) << 7;        // causal prefix width (multiple of 128)
  char* bb = base + (long)bz * BATCH_B +
             (long)(bm * (bm + 1) / 2) * TILE_B + (long)(r & 127) * 512;
  const int t = threadIdx.x;
  const bool act = (t << 3) < w;
  const int bn = t >> 4;              // tile this thread reads
  const int cl = (t << 3) & 127;      // col within tile (multiple of 8)
  const char* src = bb + (long)bn * TILE_B + (long)cl * 4;
  float v[8];
  float m = -3.0e38f;
  if (act) {
    float4 a = ((const float4*)src)[0];
    float4 b2 = ((const float4*)src)[1];
    v[0] = a.x; v[1] = a.y; v[2] = a.z; v[3] = a.w;
    v[4] = b2.x; v[5] = b2.y; v[6] = b2.z; v[7] = b2.w;
#pragma unroll
    for (int k = 0; k < 8; ++k) m = fmaxf(m, v[k]);
  }
  __shared__ float red[8];
#pragma unroll
  for (int off = 32; off > 0; off >>= 1) m = fmaxf(m, __shfl_down(m, off, 64));
  const int wid = t >> 6, lane = t & 63;
  if (lane == 0) red[wid] = m;
  __syncthreads();
  m = fmaxf(fmaxf(red[0], red[1]), fmaxf(red[2], red[3]));
  float e[8];
  float s = 0.f;
  if (act) {
#pragma unroll
    for (int k = 0; k < 8; ++k) { e[k] = __expf(v[k] - m); s += e[k]; }
  }
#pragma unroll
  for (int off = 32; off > 0; off >>= 1) s += __shfl_down(s, off, 64);
  if (lane == 0) red[4 + wid] = s;
  __syncthreads();
  s = red[4] + red[5] + red[6] + red[7];
  const float inv = 1.0f / s;
  if (act) {
    ushort4 o0, o1;
    o0.x = f2bf(e[0] * inv); o0.y = f2bf(e[1] * inv);
    o0.z = f2bf(e[2] * inv); o0.w = f2bf(e[3] * inv);
    o1.x = f2bf(e[4] * inv); o1.y = f2bf(e[5] * inv);
    o1.z = f2bf(e[6] * inv); o1.w = f2bf(e[7] * inv);
    ushort4* dst = (ushort4*)(bb + (long)bn * TILE_B + (long)cl * 2);
    dst[0] = o0;
    dst[1] = o1;
  }
}

extern "C" void kernel_launch(void* const* d_in, const int* in_sizes, int n_in,
                              void* d_out, int out_size, void* d_ws, size_t ws_size,
                              hipStream_t stream) {
  (void)in_sizes; (void)n_in; (void)out_size; (void)ws_size;
  const float* x = (const float*)d_in[0];
  const unsigned char* mask_raw = (const unsigned char*)d_in[1];
  const float* Wq = (const float*)d_in[2];
  const float* bq = (const float*)d_in[3];
  const float* Wk = (const float*)d_in[4];
  const float* bk = (const float*)d_in[5];
  const float* Wv = (const float*)d_in[6];
  const float* bv = (const float*)d_in[7];
  char* ws = (char*)d_ws;

  unsigned short* Xbf = (unsigned short*)(ws + OFF_XBF);
  unsigned short* Wbf = (unsigned short*)(ws + OFF_WBF);
  unsigned short* Qb = (unsigned short*)(ws + OFF_Q);
  unsigned short* Kb = (unsigned short*)(ws + OFF_K);
  unsigned short* Vb = (unsigned short*)(ws + OFF_V);
  unsigned short* Vt = (unsigned short*)(ws + OFF_VT);
  unsigned char* mask = (unsigned char*)(ws + OFF_MASK);
  float* meanV = (float*)(ws + OFF_MEANV);

  const long MS = (long)BB * SS;  // 16384

  // 0. canonicalize mask
  canon_mask<<<1, 256, 0, stream>>>(mask_raw, mask, (int)(BB * SS));

  // 1. fp32 -> bf16
  cvt_f32_bf16<<<2048, 256, 0, stream>>>(x, Xbf, (int)(MS * HH / 4));
  cvt_f32_bf16<<<256, 256, 0, stream>>>(Wq, Wbf, HH * HH / 4);
  cvt_f32_bf16<<<256, 256, 0, stream>>>(Wk, Wbf + HH * HH, HH * HH / 4);
  cvt_f32_bf16<<<256, 256, 0, stream>>>(Wv, Wbf + 2 * HH * HH, HH * HH / 4);

  // 2. fused QKV projection: one dispatch, z in {Q,K,V}
  gemm_bt<<<dim3(MS / BM, HH / BN, 3), 256, 0, stream>>>(
      Xbf, 0, HH, Wbf, (long)HH * HH, HH,
      (char*)Qb, (char*)Kb, (char*)Vb, 0, HH, HH, 0,
      bq, bk, bv, nullptr);

  // 3. V -> Vt ; column sums for masked-row fixup
  transpose_v<<<dim3(HH / 32, SS / 32, BB), dim3(32, 8), 0, stream>>>(Vb, Vt);
  meanv_sum<<<dim3(HH / 4, BB), 256, 0, stream>>>(Vt, meanV);

  // 4. scores: triangular grid, all 8 batches, compact tile layout
  gemm_bt<<<dim3(NTRI, 1, BB), 256, 0, stream>>>(
      Qb, (long)SS * HH, HH, Kb, (long)SS * HH, HH,
      ws + OFF_SCORES, nullptr, nullptr, BATCH_B, 0, HH, 1,
      nullptr, nullptr, nullptr, mask);

  // 5. softmax over causal prefix, in-place -> compact bf16
  softmax_tri<<<dim3(SS, BB), 256, 0, stream>>>(ws + OFF_SCORES);

  // 6. out = attn @ V (compact A, causal K-limit per block-row)
  gemm_bt<<<dim3(SS / BM, HH / BN, BB), 256, 0, stream>>>(
      (const unsigned short*)(ws + OFF_SCORES), BATCH_B / 2, 0,
      Vt, (long)SS * HH, SS,
      (char*)d_out, nullptr, nullptr, (long)SS * HH * 4, HH, SS, 2,
      nullptr, nullptr, nullptr, nullptr);

  // 7. masked query rows -> uniform mean of V
  fixup_masked<<<BB * SS, 256, 0, stream>>>((float*)d_out, mask, meanV);
}